// Round 7
// baseline (471.058 us; speedup 1.0000x reference)
//
#include <hip/hip_runtime.h>
#include <math.h>

#define NN 512
#define CS 384
#define CZ 128
#define CH 16
#define HH 12
#define PQ 4
#define PV 8

typedef float f32x4 __attribute__((ext_vector_type(4)));
typedef __bf16 bf16x8 __attribute__((ext_vector_type(8)));

// ---------------- K0: repack weights into Wcat[384][1152] + bcat[1152] ----------------
__global__ void k_repack(const float* __restrict__ Wq,  const float* __restrict__ bq,
                         const float* __restrict__ Wkv, const float* __restrict__ bkv,
                         const float* __restrict__ Wqp, const float* __restrict__ bqp,
                         const float* __restrict__ Wkvp,const float* __restrict__ bkvp,
                         float* __restrict__ Wcat, float* __restrict__ bcat)
{
    const int total = CS * 1152;
    for (int idx = blockIdx.x * blockDim.x + threadIdx.x; idx < total; idx += gridDim.x * blockDim.x) {
        int kk = idx / 1152, n = idx % 1152;
        float vv;
        if (n < 192)      vv = Wq  [kk * 192 + n];
        else if (n < 576) vv = Wkv [kk * 384 + (n - 192)];
        else if (n < 720) vv = Wqp [kk * 144 + (n - 576)];
        else              vv = Wkvp[kk * 432 + (n - 720)];
        Wcat[idx] = vv;
    }
    int n = blockIdx.x * blockDim.x + threadIdx.x;
    if (n < 1152) {
        float vv;
        if (n < 192)      vv = bq  [n];
        else if (n < 576) vv = bkv [n - 192];
        else if (n < 720) vv = bqp [n - 576];
        else              vv = bkvp[n - 720];
        bcat[n] = vv;
    }
}

// ---------------- K1: s @ Wcat — tiled GEMM, 64x64 tile, 4x4 microtile ----------------
__global__ void k_proj(const float* __restrict__ s, const float* __restrict__ Wcat,
                       const float* __restrict__ bcat,
                       float* __restrict__ q, float* __restrict__ k, float* __restrict__ v,
                       float* __restrict__ qp_raw, float* __restrict__ kvp_raw)
{
    __shared__ float As[64 * 68];
    __shared__ float Bs[64 * 64];

    int tx = threadIdx.x & 15;
    int ty = threadIdx.x >> 4;
    int n0 = blockIdx.x * 64;
    int m0 = blockIdx.y * 64;

    float acc[4][4];
    #pragma unroll
    for (int r = 0; r < 4; ++r)
        #pragma unroll
        for (int cc = 0; cc < 4; ++cc) acc[r][cc] = 0.f;

    for (int kb = 0; kb < CS; kb += 64) {
        #pragma unroll
        for (int e = 0; e < 16; ++e) {
            int idx = e * 256 + threadIdx.x;
            int m = idx >> 6, kk = idx & 63;
            As[m * 68 + kk] = s[(size_t)(m0 + m) * CS + kb + kk];
        }
        #pragma unroll
        for (int e = 0; e < 16; ++e) {
            int idx = e * 256 + threadIdx.x;
            int kk = idx >> 6, n = idx & 63;
            Bs[kk * 64 + n] = Wcat[(size_t)(kb + kk) * 1152 + n0 + n];
        }
        __syncthreads();

        for (int kk = 0; kk < 64; kk += 4) {
            f32x4 a[4], b[4];
            #pragma unroll
            for (int r = 0; r < 4; ++r)
                a[r] = *(const f32x4*)&As[(ty * 4 + r) * 68 + kk];
            #pragma unroll
            for (int kq = 0; kq < 4; ++kq)
                b[kq] = *(const f32x4*)&Bs[(kk + kq) * 64 + tx * 4];
            #pragma unroll
            for (int kq = 0; kq < 4; ++kq)
                #pragma unroll
                for (int r = 0; r < 4; ++r)
                    #pragma unroll
                    for (int cc = 0; cc < 4; ++cc)
                        acc[r][cc] += a[r][kq] * b[kq][cc];
        }
        __syncthreads();
    }

    #pragma unroll
    for (int r = 0; r < 4; ++r) {
        int i = m0 + ty * 4 + r;
        #pragma unroll
        for (int cc = 0; cc < 4; ++cc) {
            int col = n0 + tx * 4 + cc;
            float val = acc[r][cc] + bcat[col];
            if (col < 192) {
                q[i * 192 + col] = val;
            } else if (col < 576) {
                int lc = col - 192;
                int h = lc / 32, w = lc % 32;
                if (w < CH) k[(i * HH + h) * CH + w] = val;
                else        v[(i * HH + h) * CH + (w - CH)] = val;
            } else if (col < 720) {
                qp_raw[i * 144 + (col - 576)] = val;
            } else {
                kvp_raw[i * 432 + (col - 720)] = val;
            }
        }
    }
}

// ---------------- K2: rotate+translate point projections ----------------
__global__ void k_pts_transform(const float* __restrict__ qp_raw, const float* __restrict__ kvp_raw,
                                const float* __restrict__ rot, const float* __restrict__ trans,
                                float* __restrict__ q_pts, float* __restrict__ k_pts, float* __restrict__ v_pts)
{
    int idx = blockIdx.x * blockDim.x + threadIdx.x;
    const int total = NN * HH * 16;
    if (idx >= total) return;
    int i = idx / (HH * 16);
    int r = idx % (HH * 16);
    int h = r / 16;
    int p = r % 16;

    float R[9], t3[3];
    for (int a = 0; a < 9; ++a) R[a] = rot[i * 9 + a];
    for (int a = 0; a < 3; ++a) t3[a] = trans[i * 3 + a];

    float x, y, zc;
    if (p < PQ) {
        x  = qp_raw[i * 144 + 0 * 48 + h * PQ + p];
        y  = qp_raw[i * 144 + 1 * 48 + h * PQ + p];
        zc = qp_raw[i * 144 + 2 * 48 + h * PQ + p];
    } else {
        int pp = p - PQ;
        x  = kvp_raw[i * 432 + 0 * 144 + h * 12 + pp];
        y  = kvp_raw[i * 432 + 1 * 144 + h * 12 + pp];
        zc = kvp_raw[i * 432 + 2 * 144 + h * 12 + pp];
    }
    float ox = R[0] * x + R[1] * y + R[2] * zc + t3[0];
    float oy = R[3] * x + R[4] * y + R[5] * zc + t3[1];
    float oz = R[6] * x + R[7] * y + R[8] * zc + t3[2];

    if (p < PQ) {
        int o = ((i * HH + h) * PQ + p) * 3;
        q_pts[o] = ox; q_pts[o + 1] = oy; q_pts[o + 2] = oz;
    } else {
        int pp = p - PQ;
        if (pp < PQ) {
            int o = ((i * HH + h) * PQ + pp) * 3;
            k_pts[o] = ox; k_pts[o + 1] = oy; k_pts[o + 2] = oz;
        } else {
            int o = ((i * HH + h) * PV + (pp - PQ)) * 3;
            v_pts[o] = ox; v_pts[o + 1] = oy; v_pts[o + 2] = oz;
        }
    }
}

// ---------------- K2b: bias GEMM  b_bias[h,i,j] = (z @ Wb)  via bf16 MFMA ----------------
__global__ void k_bias(const float* __restrict__ z, const float* __restrict__ Wb,
                       float* __restrict__ b_bias)
{
    int i = blockIdx.x;
    int lane = threadIdx.x & 63;
    int wave = threadIdx.x >> 6;   // 0..3
    int col  = lane & 15;
    int quad = lane >> 4;

    bf16x8 bfrag[4];
    #pragma unroll
    for (int kc = 0; kc < 4; ++kc) {
        #pragma unroll
        for (int jj = 0; jj < 8; ++jj) {
            int c = kc * 32 + quad * 8 + jj;
            float wv = (col < HH) ? Wb[c * HH + col] : 0.0f;
            bfrag[kc][jj] = (__bf16)wv;
        }
    }

    for (int tt = 0; tt < 8; ++tt) {
        int j0 = (wave + 4 * tt) * 16;
        const float* zrow = z + ((size_t)i * NN + j0 + col) * CZ;
        f32x4 acc = {0.f, 0.f, 0.f, 0.f};
        #pragma unroll
        for (int kc = 0; kc < 4; ++kc) {
            float4 z0 = *(const float4*)(zrow + kc * 32 + quad * 8);
            float4 z1 = *(const float4*)(zrow + kc * 32 + quad * 8 + 4);
            bf16x8 afrag;
            afrag[0] = (__bf16)z0.x; afrag[1] = (__bf16)z0.y;
            afrag[2] = (__bf16)z0.z; afrag[3] = (__bf16)z0.w;
            afrag[4] = (__bf16)z1.x; afrag[5] = (__bf16)z1.y;
            afrag[6] = (__bf16)z1.z; afrag[7] = (__bf16)z1.w;
            acc = __builtin_amdgcn_mfma_f32_16x16x32_bf16(afrag, bfrag[kc], acc, 0, 0, 0);
        }
        if (col < HH) {
            #pragma unroll
            for (int r = 0; r < 4; ++r) {
                int j = j0 + quad * 4 + r;
                b_bias[((size_t)col * NN + i) * NN + j] = acc[r];
            }
        }
    }
}

// ---------------- K3: logits + in-block softmax (one block per i, 512 threads) --------
__global__ void k_logits(const float* __restrict__ b_bias, const float* __restrict__ bb,
                         const float* __restrict__ q, const float* __restrict__ k,
                         const float* __restrict__ q_pts, const float* __restrict__ k_pts,
                         const float* __restrict__ head_weights,
                         const float* __restrict__ mask,
                         float* __restrict__ a_out)
{
    __shared__ float lgs[HH][NN];   // 24 KB
    __shared__ float q_lds[HH * CH];
    __shared__ float qp_lds[HH * PQ * 3];
    __shared__ float hw_lds[HH];

    int i = blockIdx.x;
    int j = threadIdx.x;           // 512 threads

    for (int t = j; t < HH * CH; t += 512) q_lds[t] = q[i * HH * CH + t];
    for (int t = j; t < HH * PQ * 3; t += 512) qp_lds[t] = q_pts[i * HH * PQ * 3 + t];
    if (j < HH) {
        float x = head_weights[j];
        hw_lds[j] = log1pf(expf(x)) * sqrtf(1.0f / 54.0f);
    }
    __syncthreads();

    const float qk_scale = sqrtf(1.0f / 48.0f);
    const float b_scale  = sqrtf(1.0f / 3.0f);
    float sqm = 100000.0f * (mask[i] * mask[j] - 1.0f);

    #pragma unroll
    for (int h = 0; h < HH; ++h) {
        float bias_h = b_bias[((size_t)h * NN + i) * NN + j] + bb[h];
        float acc = 0.f;
        const float* kr = k + ((size_t)j * HH + h) * CH;
        #pragma unroll
        for (int c = 0; c < CH; ++c) acc += q_lds[h * CH + c] * kr[c];
        float s2 = 0.f;
        #pragma unroll
        for (int p = 0; p < PQ; ++p) {
            const float* kp = k_pts + (((size_t)j * HH + h) * PQ + p) * 3;
            float dx = qp_lds[(h * PQ + p) * 3 + 0] - kp[0];
            float dy = qp_lds[(h * PQ + p) * 3 + 1] - kp[1];
            float dz = qp_lds[(h * PQ + p) * 3 + 2] - kp[2];
            s2 += dx * dx + dy * dy + dz * dz;
        }
        lgs[h][j] = acc * qk_scale + b_scale * bias_h - 0.5f * hw_lds[h] * s2 + sqm;
    }
    __syncthreads();

    // softmax: 8 waves, wave w handles rows w, w+8
    int wave = j >> 6, lane = j & 63;
    for (int row = wave; row < HH; row += 8) {
        float vals[8];
        float m = -1e30f;
        #pragma unroll
        for (int u = 0; u < 8; ++u) { vals[u] = lgs[row][lane + u * 64]; m = fmaxf(m, vals[u]); }
        #pragma unroll
        for (int off = 32; off >= 1; off >>= 1) m = fmaxf(m, __shfl_xor(m, off));
        float ssum = 0.f;
        #pragma unroll
        for (int u = 0; u < 8; ++u) { vals[u] = expf(vals[u] - m); ssum += vals[u]; }
        #pragma unroll
        for (int off = 32; off >= 1; off >>= 1) ssum += __shfl_xor(ssum, off);
        float inv = 1.0f / ssum;
        #pragma unroll
        for (int u = 0; u < 8; ++u) lgs[row][lane + u * 64] = vals[u] * inv;
    }
    __syncthreads();

    #pragma unroll
    for (int h = 0; h < HH; ++h)
        a_out[((size_t)h * NN + i) * NN + j] = lgs[h][j];
}

// ---------------- K5: o = a·v and o_pt = a·v_pts (+ inverse frame, norms) ----------------
__global__ void k_out_ov(const float* __restrict__ a, const float* __restrict__ v,
                         const float* __restrict__ v_pts,
                         const float* __restrict__ rot, const float* __restrict__ trans,
                         float* __restrict__ cat)
{
    __shared__ float a_lds[HH][NN];
    __shared__ float opt_lds[HH * PV * 3];
    int i = blockIdx.x;
    for (int h = 0; h < HH; ++h)
        for (int j = threadIdx.x; j < NN; j += 256)
            a_lds[h][j] = a[((size_t)h * NN + i) * NN + j];
    __syncthreads();

    for (int out = threadIdx.x; out < 480; out += 256) {
        float acc = 0.f;
        if (out < 192) {
            int h = out / CH;
            for (int j = 0; j < NN; ++j)
                acc += a_lds[h][j] * v[(size_t)j * 192 + out];
            cat[(size_t)i * 2112 + out] = acc;
        } else {
            int r = out - 192;
            int h = r / (PV * 3);
            for (int j = 0; j < NN; ++j)
                acc += a_lds[h][j] * v_pts[(size_t)j * (HH * PV * 3) + r];
            opt_lds[r] = acc;
        }
    }
    __syncthreads();

    if (threadIdx.x < HH * PV) {
        int hp = threadIdx.x;
        float R[9], t3[3];
        for (int a2 = 0; a2 < 9; ++a2) R[a2] = rot[i * 9 + a2];
        for (int a2 = 0; a2 < 3; ++a2) t3[a2] = trans[i * 3 + a2];
        float gx = opt_lds[hp * 3 + 0] - t3[0];
        float gy = opt_lds[hp * 3 + 1] - t3[1];
        float gz = opt_lds[hp * 3 + 2] - t3[2];
        float lx = R[0] * gx + R[3] * gy + R[6] * gz;
        float ly = R[1] * gx + R[4] * gy + R[7] * gz;
        float lz = R[2] * gx + R[5] * gy + R[8] * gz;
        float* crow = cat + (size_t)i * 2112;
        crow[192 + 0 * 96 + hp] = lx;
        crow[192 + 1 * 96 + hp] = ly;
        crow[192 + 2 * 96 + hp] = lz;
        crow[480 + hp] = sqrtf(lx * lx + ly * ly + lz * lz + 1e-8f);
    }
}

// ---------------- K6: o_pair[h,c] = sum_j a[h,j] * z[i,j,c] — per-i bf16 MFMA ----------
// M = 16 (12 heads + pad), N = 128 (c), K = 512 (j). 4 waves x 2 n-tiles.
#define ALDS_STRIDE 516   // 516*4 B: h-row stride; (h*516)%32 = h*4 -> 2-way on frag reads (free)
__global__ void __launch_bounds__(256)
k_out_pair(const float* __restrict__ a, const float* __restrict__ z,
           float* __restrict__ cat)
{
    __shared__ float a_lds[HH * ALDS_STRIDE];  // 24.2 KB

    int i = blockIdx.x;
    int tid = threadIdx.x;
    int lane = tid & 63;
    int wave = tid >> 6;       // 0..3
    int col  = lane & 15;
    int quad = lane >> 4;

    for (int t = tid; t < HH * NN; t += 256) {
        int h = t >> 9, j = t & 511;
        a_lds[h * ALDS_STRIDE + j] = a[((size_t)h * NN + i) * NN + j];
    }
    __syncthreads();

    int hc = (col < HH) ? col : (HH - 1);   // A-row clamp for pad rows
    f32x4 acc0 = {0.f, 0.f, 0.f, 0.f};
    f32x4 acc1 = {0.f, 0.f, 0.f, 0.f};
    int c0 = (wave * 2 + 0) * 16 + col;
    int c1 = (wave * 2 + 1) * 16 + col;

    for (int ks = 0; ks < 16; ++ks) {
        int k0 = ks * 32 + quad * 8;
        const float* arow = &a_lds[hc * ALDS_STRIDE + k0];
        bf16x8 af;
        #pragma unroll
        for (int jj = 0; jj < 8; ++jj) af[jj] = (__bf16)arow[jj];

        const float* zrow = z + ((size_t)i * NN + k0) * CZ;
        bf16x8 bf0, bf1;
        #pragma unroll
        for (int jj = 0; jj < 8; ++jj) bf0[jj] = (__bf16)zrow[(size_t)jj * CZ + c0];
        #pragma unroll
        for (int jj = 0; jj < 8; ++jj) bf1[jj] = (__bf16)zrow[(size_t)jj * CZ + c1];

        acc0 = __builtin_amdgcn_mfma_f32_16x16x32_bf16(af, bf0, acc0, 0, 0, 0);
        acc1 = __builtin_amdgcn_mfma_f32_16x16x32_bf16(af, bf1, acc1, 0, 0, 0);
    }

    float* crow = cat + (size_t)i * 2112 + 576;
    #pragma unroll
    for (int r = 0; r < 4; ++r) {
        int h = quad * 4 + r;
        if (h < HH) {
            crow[h * CZ + c0] = acc0[r];
            crow[h * CZ + c1] = acc1[r];
        }
    }
}

// ---------------- K7: out = cat @ Wout + bout — tiled split-K GEMM ----------------
__global__ void k_final(const float* __restrict__ cat, const float* __restrict__ Wout,
                        const float* __restrict__ bout, float* __restrict__ out)
{
    __shared__ float As[64 * 52];
    __shared__ float Bs[48 * 64];

    int tx = threadIdx.x & 15;
    int ty = threadIdx.x >> 4;
    int n0 = blockIdx.x * 64;
    int m0 = blockIdx.y * 64;
    int k0 = blockIdx.z * 528;

    float acc[4][4];
    #pragma unroll
    for (int r = 0; r < 4; ++r)
        #pragma unroll
        for (int cc = 0; cc < 4; ++cc) acc[r][cc] = 0.f;

    for (int stage = 0; stage < 11; ++stage) {
        int kb = k0 + stage * 48;
        #pragma unroll
        for (int e = 0; e < 12; ++e) {
            int idx = e * 256 + threadIdx.x;
            int m = idx / 48, kk = idx % 48;
            As[m * 52 + kk] = cat[(size_t)(m0 + m) * 2112 + kb + kk];
        }
        #pragma unroll
        for (int e = 0; e < 12; ++e) {
            int idx = e * 256 + threadIdx.x;
            int kk = idx >> 6, n = idx & 63;
            Bs[kk * 64 + n] = Wout[(size_t)(kb + kk) * 384 + n0 + n];
        }
        __syncthreads();

        for (int kk = 0; kk < 48; kk += 4) {
            f32x4 a[4], b[4];
            #pragma unroll
            for (int r = 0; r < 4; ++r)
                a[r] = *(const f32x4*)&As[(ty * 4 + r) * 52 + kk];
            #pragma unroll
            for (int kq = 0; kq < 4; ++kq)
                b[kq] = *(const f32x4*)&Bs[(kk + kq) * 64 + tx * 4];
            #pragma unroll
            for (int kq = 0; kq < 4; ++kq)
                #pragma unroll
                for (int r = 0; r < 4; ++r)
                    #pragma unroll
                    for (int cc = 0; cc < 4; ++cc)
                        acc[r][cc] += a[r][kq] * b[kq][cc];
        }
        __syncthreads();
    }

    bool add_bias = (blockIdx.z == 0);
    #pragma unroll
    for (int r = 0; r < 4; ++r) {
        int m = m0 + ty * 4 + r;
        #pragma unroll
        for (int cc = 0; cc < 4; ++cc) {
            int n = n0 + tx * 4 + cc;
            float val = acc[r][cc] + (add_bias ? bout[n] : 0.f);
            atomicAdd(&out[(size_t)m * 384 + n], val);
        }
    }
}

extern "C" void kernel_launch(void* const* d_in, const int* in_sizes, int n_in,
                              void* d_out, int out_size, void* d_ws, size_t ws_size,
                              hipStream_t stream)
{
    const float* s     = (const float*)d_in[0];
    const float* z     = (const float*)d_in[1];
    const float* rot   = (const float*)d_in[2];
    const float* trans = (const float*)d_in[3];
    const float* mask  = (const float*)d_in[4];
    const float* Wq    = (const float*)d_in[5];
    const float* bq    = (const float*)d_in[6];
    const float* Wkv   = (const float*)d_in[7];
    const float* bkv   = (const float*)d_in[8];
    const float* Wqp   = (const float*)d_in[9];
    const float* bqp   = (const float*)d_in[10];
    const float* Wkvp  = (const float*)d_in[11];
    const float* bkvp  = (const float*)d_in[12];
    const float* Wb    = (const float*)d_in[13];
    const float* bb    = (const float*)d_in[14];
    const float* hw    = (const float*)d_in[15];
    const float* Wout  = (const float*)d_in[16];
    const float* bout  = (const float*)d_in[17];
    float* out = (float*)d_out;

    float* ws = (float*)d_ws;
    float* q       = ws;            // 98304
    float* k       = ws + 98304;    // 98304
    float* v       = ws + 196608;   // 98304
    float* qp_raw  = ws + 294912;   // 73728
    float* kvp_raw = ws + 368640;   // 221184
    float* q_pts   = ws + 589824;   // 73728
    float* k_pts   = ws + 663552;   // 73728
    float* v_pts   = ws + 737280;   // 147456
    float* a_buf   = ws + 884736;   // 3145728 (softmaxed attention)
    float* b_bias  = ws + 4030464;  // 3145728
    float* cat     = ws + 7176192;  // 1081344
    float* Wcat    = ws + 8257536;  // 442368
    float* bcat    = ws + 8699904;  // 1152

    hipMemsetAsync(out, 0, (size_t)NN * CS * sizeof(float), stream);

    hipLaunchKernelGGL(k_repack, dim3(512), dim3(256), 0, stream,
                       Wq, bq, Wkv, bkv, Wqp, bqp, Wkvp, bkvp, Wcat, bcat);
    hipLaunchKernelGGL(k_proj, dim3(18, 8), dim3(256), 0, stream,
                       s, Wcat, bcat, q, k, v, qp_raw, kvp_raw);
    hipLaunchKernelGGL(k_pts_transform, dim3(384), dim3(256), 0, stream,
                       qp_raw, kvp_raw, rot, trans, q_pts, k_pts, v_pts);
    hipLaunchKernelGGL(k_bias, dim3(NN), dim3(256), 0, stream, z, Wb, b_bias);
    hipLaunchKernelGGL(k_logits, dim3(NN), dim3(512), 0, stream,
                       b_bias, bb, q, k, q_pts, k_pts, hw, mask, a_buf);
    hipLaunchKernelGGL(k_out_ov, dim3(NN), dim3(256), 0, stream,
                       a_buf, v, v_pts, rot, trans, cat);
    hipLaunchKernelGGL(k_out_pair, dim3(NN), dim3(256), 0, stream, a_buf, z, cat);
    hipLaunchKernelGGL(k_final, dim3(6, 8, 4), dim3(256), 0, stream, cat, Wout, bout, out);
}

// Round 8
// 415.702 us; speedup vs baseline: 1.1332x; 1.1332x over previous
//
#include <hip/hip_runtime.h>
#include <math.h>

#define NN 512
#define CS 384
#define CZ 128
#define CH 16
#define HH 12
#define PQ 4
#define PV 8

typedef float f32x4 __attribute__((ext_vector_type(4)));
typedef __bf16 bf16x8 __attribute__((ext_vector_type(8)));

// ---------------- K0: repack weights into Wcat[384][1152] + bcat[1152] ----------------
__global__ void k_repack(const float* __restrict__ Wq,  const float* __restrict__ bq,
                         const float* __restrict__ Wkv, const float* __restrict__ bkv,
                         const float* __restrict__ Wqp, const float* __restrict__ bqp,
                         const float* __restrict__ Wkvp,const float* __restrict__ bkvp,
                         float* __restrict__ Wcat, float* __restrict__ bcat)
{
    const int total = CS * 1152;
    for (int idx = blockIdx.x * blockDim.x + threadIdx.x; idx < total; idx += gridDim.x * blockDim.x) {
        int kk = idx / 1152, n = idx % 1152;
        float vv;
        if (n < 192)      vv = Wq  [kk * 192 + n];
        else if (n < 576) vv = Wkv [kk * 384 + (n - 192)];
        else if (n < 720) vv = Wqp [kk * 144 + (n - 576)];
        else              vv = Wkvp[kk * 432 + (n - 720)];
        Wcat[idx] = vv;
    }
    int n = blockIdx.x * blockDim.x + threadIdx.x;
    if (n < 1152) {
        float vv;
        if (n < 192)      vv = bq  [n];
        else if (n < 576) vv = bkv [n - 192];
        else if (n < 720) vv = bqp [n - 576];
        else              vv = bkvp[n - 720];
        bcat[n] = vv;
    }
}

// ---------------- K1: s @ Wcat — tiled GEMM; k written TRANSPOSED (j fastest) --------
__global__ void k_proj(const float* __restrict__ s, const float* __restrict__ Wcat,
                       const float* __restrict__ bcat,
                       float* __restrict__ q, float* __restrict__ k_t, float* __restrict__ v,
                       float* __restrict__ qp_raw, float* __restrict__ kvp_raw)
{
    __shared__ float As[64 * 68];
    __shared__ float Bs[64 * 64];

    int tx = threadIdx.x & 15;
    int ty = threadIdx.x >> 4;
    int n0 = blockIdx.x * 64;
    int m0 = blockIdx.y * 64;

    float acc[4][4];
    #pragma unroll
    for (int r = 0; r < 4; ++r)
        #pragma unroll
        for (int cc = 0; cc < 4; ++cc) acc[r][cc] = 0.f;

    for (int kb = 0; kb < CS; kb += 64) {
        #pragma unroll
        for (int e = 0; e < 16; ++e) {
            int idx = e * 256 + threadIdx.x;
            int m = idx >> 6, kk = idx & 63;
            As[m * 68 + kk] = s[(size_t)(m0 + m) * CS + kb + kk];
        }
        #pragma unroll
        for (int e = 0; e < 16; ++e) {
            int idx = e * 256 + threadIdx.x;
            int kk = idx >> 6, n = idx & 63;
            Bs[kk * 64 + n] = Wcat[(size_t)(kb + kk) * 1152 + n0 + n];
        }
        __syncthreads();

        for (int kk = 0; kk < 64; kk += 4) {
            f32x4 a[4], b[4];
            #pragma unroll
            for (int r = 0; r < 4; ++r)
                a[r] = *(const f32x4*)&As[(ty * 4 + r) * 68 + kk];
            #pragma unroll
            for (int kq = 0; kq < 4; ++kq)
                b[kq] = *(const f32x4*)&Bs[(kk + kq) * 64 + tx * 4];
            #pragma unroll
            for (int kq = 0; kq < 4; ++kq)
                #pragma unroll
                for (int r = 0; r < 4; ++r)
                    #pragma unroll
                    for (int cc = 0; cc < 4; ++cc)
                        acc[r][cc] += a[r][kq] * b[kq][cc];
        }
        __syncthreads();
    }

    #pragma unroll
    for (int r = 0; r < 4; ++r) {
        int i = m0 + ty * 4 + r;
        #pragma unroll
        for (int cc = 0; cc < 4; ++cc) {
            int col = n0 + tx * 4 + cc;
            float val = acc[r][cc] + bcat[col];
            if (col < 192) {
                q[i * 192 + col] = val;
            } else if (col < 576) {
                int lc = col - 192;
                int h = lc / 32, w = lc % 32;
                if (w < CH) k_t[(h * CH + w) * NN + i] = val;   // transposed
                else        v[(i * HH + h) * CH + (w - CH)] = val;
            } else if (col < 720) {
                qp_raw[i * 144 + (col - 576)] = val;
            } else {
                kvp_raw[i * 432 + (col - 720)] = val;
            }
        }
    }
}

// ---------------- K2: rotate+translate; k_pts written TRANSPOSED (j fastest) ---------
__global__ void k_pts_transform(const float* __restrict__ qp_raw, const float* __restrict__ kvp_raw,
                                const float* __restrict__ rot, const float* __restrict__ trans,
                                float* __restrict__ q_pts, float* __restrict__ k_pts_t,
                                float* __restrict__ v_pts)
{
    int idx = blockIdx.x * blockDim.x + threadIdx.x;
    const int total = NN * HH * 16;
    if (idx >= total) return;
    int i = idx / (HH * 16);
    int r = idx % (HH * 16);
    int h = r / 16;
    int p = r % 16;

    float R[9], t3[3];
    for (int a = 0; a < 9; ++a) R[a] = rot[i * 9 + a];
    for (int a = 0; a < 3; ++a) t3[a] = trans[i * 3 + a];

    float x, y, zc;
    if (p < PQ) {
        x  = qp_raw[i * 144 + 0 * 48 + h * PQ + p];
        y  = qp_raw[i * 144 + 1 * 48 + h * PQ + p];
        zc = qp_raw[i * 144 + 2 * 48 + h * PQ + p];
    } else {
        int pp = p - PQ;
        x  = kvp_raw[i * 432 + 0 * 144 + h * 12 + pp];
        y  = kvp_raw[i * 432 + 1 * 144 + h * 12 + pp];
        zc = kvp_raw[i * 432 + 2 * 144 + h * 12 + pp];
    }
    float ox = R[0] * x + R[1] * y + R[2] * zc + t3[0];
    float oy = R[3] * x + R[4] * y + R[5] * zc + t3[1];
    float oz = R[6] * x + R[7] * y + R[8] * zc + t3[2];

    if (p < PQ) {
        int o = ((i * HH + h) * PQ + p) * 3;
        q_pts[o] = ox; q_pts[o + 1] = oy; q_pts[o + 2] = oz;
    } else {
        int pp = p - PQ;
        if (pp < PQ) {
            int rb = (h * PQ + pp) * 3;
            k_pts_t[(size_t)(rb + 0) * NN + i] = ox;   // transposed
            k_pts_t[(size_t)(rb + 1) * NN + i] = oy;
            k_pts_t[(size_t)(rb + 2) * NN + i] = oz;
        } else {
            int o = ((i * HH + h) * PV + (pp - PQ)) * 3;
            v_pts[o] = ox; v_pts[o + 1] = oy; v_pts[o + 2] = oz;
        }
    }
}

// ---------------- K2b: bias GEMM  b_bias[h,i,j] = (z @ Wb)  via bf16 MFMA ----------------
__global__ void k_bias(const float* __restrict__ z, const float* __restrict__ Wb,
                       float* __restrict__ b_bias)
{
    int i = blockIdx.x;
    int lane = threadIdx.x & 63;
    int wave = threadIdx.x >> 6;   // 0..3
    int col  = lane & 15;
    int quad = lane >> 4;

    bf16x8 bfrag[4];
    #pragma unroll
    for (int kc = 0; kc < 4; ++kc) {
        #pragma unroll
        for (int jj = 0; jj < 8; ++jj) {
            int c = kc * 32 + quad * 8 + jj;
            float wv = (col < HH) ? Wb[c * HH + col] : 0.0f;
            bfrag[kc][jj] = (__bf16)wv;
        }
    }

    for (int tt = 0; tt < 8; ++tt) {
        int j0 = (wave + 4 * tt) * 16;
        const float* zrow = z + ((size_t)i * NN + j0 + col) * CZ;
        f32x4 acc = {0.f, 0.f, 0.f, 0.f};
        #pragma unroll
        for (int kc = 0; kc < 4; ++kc) {
            float4 z0 = *(const float4*)(zrow + kc * 32 + quad * 8);
            float4 z1 = *(const float4*)(zrow + kc * 32 + quad * 8 + 4);
            bf16x8 afrag;
            afrag[0] = (__bf16)z0.x; afrag[1] = (__bf16)z0.y;
            afrag[2] = (__bf16)z0.z; afrag[3] = (__bf16)z0.w;
            afrag[4] = (__bf16)z1.x; afrag[5] = (__bf16)z1.y;
            afrag[6] = (__bf16)z1.z; afrag[7] = (__bf16)z1.w;
            acc = __builtin_amdgcn_mfma_f32_16x16x32_bf16(afrag, bfrag[kc], acc, 0, 0, 0);
        }
        if (col < HH) {
            #pragma unroll
            for (int r = 0; r < 4; ++r) {
                int j = j0 + quad * 4 + r;
                b_bias[((size_t)col * NN + i) * NN + j] = acc[r];
            }
        }
    }
}

// ---------------- K3: logits + in-block softmax (coalesced k_t / k_pts_t reads) ------
__global__ void k_logits(const float* __restrict__ b_bias, const float* __restrict__ bb,
                         const float* __restrict__ q, const float* __restrict__ k_t,
                         const float* __restrict__ q_pts, const float* __restrict__ k_pts_t,
                         const float* __restrict__ head_weights,
                         const float* __restrict__ mask,
                         float* __restrict__ a_out)
{
    __shared__ float lgs[HH][NN];   // 24 KB
    __shared__ float q_lds[HH * CH];
    __shared__ float qp_lds[HH * PQ * 3];
    __shared__ float hw_lds[HH];

    int i = blockIdx.x;
    int j = threadIdx.x;           // 512 threads

    for (int t = j; t < HH * CH; t += 512) q_lds[t] = q[i * HH * CH + t];
    for (int t = j; t < HH * PQ * 3; t += 512) qp_lds[t] = q_pts[i * HH * PQ * 3 + t];
    if (j < HH) {
        float x = head_weights[j];
        hw_lds[j] = log1pf(expf(x)) * sqrtf(1.0f / 54.0f);
    }
    __syncthreads();

    const float qk_scale = sqrtf(1.0f / 48.0f);
    const float b_scale  = sqrtf(1.0f / 3.0f);
    float sqm = 100000.0f * (mask[i] * mask[j] - 1.0f);

    #pragma unroll
    for (int h = 0; h < HH; ++h) {
        float bias_h = b_bias[((size_t)h * NN + i) * NN + j] + bb[h];
        float acc = 0.f;
        #pragma unroll
        for (int c = 0; c < CH; ++c)
            acc += q_lds[h * CH + c] * k_t[(size_t)(h * CH + c) * NN + j];
        float s2 = 0.f;
        #pragma unroll
        for (int p = 0; p < PQ; ++p) {
            int rb = (h * PQ + p) * 3;
            float dx = qp_lds[rb + 0] - k_pts_t[(size_t)(rb + 0) * NN + j];
            float dy = qp_lds[rb + 1] - k_pts_t[(size_t)(rb + 1) * NN + j];
            float dz = qp_lds[rb + 2] - k_pts_t[(size_t)(rb + 2) * NN + j];
            s2 += dx * dx + dy * dy + dz * dz;
        }
        lgs[h][j] = acc * qk_scale + b_scale * bias_h - 0.5f * hw_lds[h] * s2 + sqm;
    }
    __syncthreads();

    // softmax: 8 waves, wave w handles rows w, w+8
    int wave = j >> 6, lane = j & 63;
    for (int row = wave; row < HH; row += 8) {
        float vals[8];
        float m = -1e30f;
        #pragma unroll
        for (int u = 0; u < 8; ++u) { vals[u] = lgs[row][lane + u * 64]; m = fmaxf(m, vals[u]); }
        #pragma unroll
        for (int off = 32; off >= 1; off >>= 1) m = fmaxf(m, __shfl_xor(m, off));
        float ssum = 0.f;
        #pragma unroll
        for (int u = 0; u < 8; ++u) { vals[u] = expf(vals[u] - m); ssum += vals[u]; }
        #pragma unroll
        for (int off = 32; off >= 1; off >>= 1) ssum += __shfl_xor(ssum, off);
        float inv = 1.0f / ssum;
        #pragma unroll
        for (int u = 0; u < 8; ++u) lgs[row][lane + u * 64] = vals[u] * inv;
    }
    __syncthreads();

    #pragma unroll
    for (int h = 0; h < HH; ++h)
        a_out[((size_t)h * NN + i) * NN + j] = lgs[h][j];
}

// ---------------- K5: o = a·v and o_pt = a·v_pts (+ inverse frame, norms) ----------------
__global__ void k_out_ov(const float* __restrict__ a, const float* __restrict__ v,
                         const float* __restrict__ v_pts,
                         const float* __restrict__ rot, const float* __restrict__ trans,
                         float* __restrict__ cat)
{
    __shared__ float a_lds[HH][NN];
    __shared__ float opt_lds[HH * PV * 3];
    int i = blockIdx.x;
    for (int h = 0; h < HH; ++h)
        for (int j = threadIdx.x; j < NN; j += 256)
            a_lds[h][j] = a[((size_t)h * NN + i) * NN + j];
    __syncthreads();

    for (int out = threadIdx.x; out < 480; out += 256) {
        float acc = 0.f;
        if (out < 192) {
            int h = out / CH;
            for (int j = 0; j < NN; ++j)
                acc += a_lds[h][j] * v[(size_t)j * 192 + out];
            cat[(size_t)i * 2112 + out] = acc;
        } else {
            int r = out - 192;
            int h = r / (PV * 3);
            for (int j = 0; j < NN; ++j)
                acc += a_lds[h][j] * v_pts[(size_t)j * (HH * PV * 3) + r];
            opt_lds[r] = acc;
        }
    }
    __syncthreads();

    if (threadIdx.x < HH * PV) {
        int hp = threadIdx.x;
        float R[9], t3[3];
        for (int a2 = 0; a2 < 9; ++a2) R[a2] = rot[i * 9 + a2];
        for (int a2 = 0; a2 < 3; ++a2) t3[a2] = trans[i * 3 + a2];
        float gx = opt_lds[hp * 3 + 0] - t3[0];
        float gy = opt_lds[hp * 3 + 1] - t3[1];
        float gz = opt_lds[hp * 3 + 2] - t3[2];
        float lx = R[0] * gx + R[3] * gy + R[6] * gz;
        float ly = R[1] * gx + R[4] * gy + R[7] * gz;
        float lz = R[2] * gx + R[5] * gy + R[8] * gz;
        float* crow = cat + (size_t)i * 2112;
        crow[192 + 0 * 96 + hp] = lx;
        crow[192 + 1 * 96 + hp] = ly;
        crow[192 + 2 * 96 + hp] = lz;
        crow[480 + hp] = sqrtf(lx * lx + ly * ly + lz * lz + 1e-8f);
    }
}

// ---------------- K6: o_pair[h,c] = sum_j a[h,j] * z[i,j,c] — per-i bf16 MFMA ----------
#define ALDS_STRIDE 516
__global__ void __launch_bounds__(256)
k_out_pair(const float* __restrict__ a, const float* __restrict__ z,
           float* __restrict__ cat)
{
    __shared__ float a_lds[HH * ALDS_STRIDE];  // 24.2 KB

    int i = blockIdx.x;
    int tid = threadIdx.x;
    int lane = tid & 63;
    int wave = tid >> 6;       // 0..3
    int col  = lane & 15;
    int quad = lane >> 4;

    for (int t = tid; t < HH * NN; t += 256) {
        int h = t >> 9, j = t & 511;
        a_lds[h * ALDS_STRIDE + j] = a[((size_t)h * NN + i) * NN + j];
    }
    __syncthreads();

    int hc = (col < HH) ? col : (HH - 1);
    f32x4 acc0 = {0.f, 0.f, 0.f, 0.f};
    f32x4 acc1 = {0.f, 0.f, 0.f, 0.f};
    int c0 = (wave * 2 + 0) * 16 + col;
    int c1 = (wave * 2 + 1) * 16 + col;

    for (int ks = 0; ks < 16; ++ks) {
        int k0 = ks * 32 + quad * 8;
        const float* arow = &a_lds[hc * ALDS_STRIDE + k0];
        bf16x8 af;
        #pragma unroll
        for (int jj = 0; jj < 8; ++jj) af[jj] = (__bf16)arow[jj];

        const float* zrow = z + ((size_t)i * NN + k0) * CZ;
        bf16x8 bf0, bf1;
        #pragma unroll
        for (int jj = 0; jj < 8; ++jj) bf0[jj] = (__bf16)zrow[(size_t)jj * CZ + c0];
        #pragma unroll
        for (int jj = 0; jj < 8; ++jj) bf1[jj] = (__bf16)zrow[(size_t)jj * CZ + c1];

        acc0 = __builtin_amdgcn_mfma_f32_16x16x32_bf16(af, bf0, acc0, 0, 0, 0);
        acc1 = __builtin_amdgcn_mfma_f32_16x16x32_bf16(af, bf1, acc1, 0, 0, 0);
    }

    float* crow = cat + (size_t)i * 2112 + 576;
    #pragma unroll
    for (int r = 0; r < 4; ++r) {
        int h = quad * 4 + r;
        if (h < HH) {
            crow[h * CZ + c0] = acc0[r];
            crow[h * CZ + c1] = acc1[r];
        }
    }
}

// ---------------- K7: out = cat @ Wout + bout — tiled split-K GEMM ----------------
__global__ void k_final(const float* __restrict__ cat, const float* __restrict__ Wout,
                        const float* __restrict__ bout, float* __restrict__ out)
{
    __shared__ float As[64 * 52];
    __shared__ float Bs[48 * 64];

    int tx = threadIdx.x & 15;
    int ty = threadIdx.x >> 4;
    int n0 = blockIdx.x * 64;
    int m0 = blockIdx.y * 64;
    int k0 = blockIdx.z * 528;

    float acc[4][4];
    #pragma unroll
    for (int r = 0; r < 4; ++r)
        #pragma unroll
        for (int cc = 0; cc < 4; ++cc) acc[r][cc] = 0.f;

    for (int stage = 0; stage < 11; ++stage) {
        int kb = k0 + stage * 48;
        #pragma unroll
        for (int e = 0; e < 12; ++e) {
            int idx = e * 256 + threadIdx.x;
            int m = idx / 48, kk = idx % 48;
            As[m * 52 + kk] = cat[(size_t)(m0 + m) * 2112 + kb + kk];
        }
        #pragma unroll
        for (int e = 0; e < 12; ++e) {
            int idx = e * 256 + threadIdx.x;
            int kk = idx >> 6, n = idx & 63;
            Bs[kk * 64 + n] = Wout[(size_t)(kb + kk) * 384 + n0 + n];
        }
        __syncthreads();

        for (int kk = 0; kk < 48; kk += 4) {
            f32x4 a[4], b[4];
            #pragma unroll
            for (int r = 0; r < 4; ++r)
                a[r] = *(const f32x4*)&As[(ty * 4 + r) * 52 + kk];
            #pragma unroll
            for (int kq = 0; kq < 4; ++kq)
                b[kq] = *(const f32x4*)&Bs[(kk + kq) * 64 + tx * 4];
            #pragma unroll
            for (int kq = 0; kq < 4; ++kq)
                #pragma unroll
                for (int r = 0; r < 4; ++r)
                    #pragma unroll
                    for (int cc = 0; cc < 4; ++cc)
                        acc[r][cc] += a[r][kq] * b[kq][cc];
        }
        __syncthreads();
    }

    bool add_bias = (blockIdx.z == 0);
    #pragma unroll
    for (int r = 0; r < 4; ++r) {
        int m = m0 + ty * 4 + r;
        #pragma unroll
        for (int cc = 0; cc < 4; ++cc) {
            int n = n0 + tx * 4 + cc;
            float val = acc[r][cc] + (add_bias ? bout[n] : 0.f);
            atomicAdd(&out[(size_t)m * 384 + n], val);
        }
    }
}

extern "C" void kernel_launch(void* const* d_in, const int* in_sizes, int n_in,
                              void* d_out, int out_size, void* d_ws, size_t ws_size,
                              hipStream_t stream)
{
    const float* s     = (const float*)d_in[0];
    const float* z     = (const float*)d_in[1];
    const float* rot   = (const float*)d_in[2];
    const float* trans = (const float*)d_in[3];
    const float* mask  = (const float*)d_in[4];
    const float* Wq    = (const float*)d_in[5];
    const float* bq    = (const float*)d_in[6];
    const float* Wkv   = (const float*)d_in[7];
    const float* bkv   = (const float*)d_in[8];
    const float* Wqp   = (const float*)d_in[9];
    const float* bqp   = (const float*)d_in[10];
    const float* Wkvp  = (const float*)d_in[11];
    const float* bkvp  = (const float*)d_in[12];
    const float* Wb    = (const float*)d_in[13];
    const float* bb    = (const float*)d_in[14];
    const float* hw    = (const float*)d_in[15];
    const float* Wout  = (const float*)d_in[16];
    const float* bout  = (const float*)d_in[17];
    float* out = (float*)d_out;

    float* ws = (float*)d_ws;
    float* q       = ws;            // 98304
    float* k_t     = ws + 98304;    // 98304 (transposed)
    float* v       = ws + 196608;   // 98304
    float* qp_raw  = ws + 294912;   // 73728
    float* kvp_raw = ws + 368640;   // 221184
    float* q_pts   = ws + 589824;   // 73728
    float* k_pts_t = ws + 663552;   // 73728 (transposed)
    float* v_pts   = ws + 737280;   // 147456
    float* a_buf   = ws + 884736;   // 3145728
    float* b_bias  = ws + 4030464;  // 3145728
    float* cat     = ws + 7176192;  // 1081344
    float* Wcat    = ws + 8257536;  // 442368
    float* bcat    = ws + 8699904;  // 1152

    hipMemsetAsync(out, 0, (size_t)NN * CS * sizeof(float), stream);

    hipLaunchKernelGGL(k_repack, dim3(512), dim3(256), 0, stream,
                       Wq, bq, Wkv, bkv, Wqp, bqp, Wkvp, bkvp, Wcat, bcat);
    hipLaunchKernelGGL(k_proj, dim3(18, 8), dim3(256), 0, stream,
                       s, Wcat, bcat, q, k_t, v, qp_raw, kvp_raw);
    hipLaunchKernelGGL(k_pts_transform, dim3(384), dim3(256), 0, stream,
                       qp_raw, kvp_raw, rot, trans, q_pts, k_pts_t, v_pts);
    hipLaunchKernelGGL(k_bias, dim3(NN), dim3(256), 0, stream, z, Wb, b_bias);
    hipLaunchKernelGGL(k_logits, dim3(NN), dim3(512), 0, stream,
                       b_bias, bb, q, k_t, q_pts, k_pts_t, hw, mask, a_buf);
    hipLaunchKernelGGL(k_out_ov, dim3(NN), dim3(256), 0, stream,
                       a_buf, v, v_pts, rot, trans, cat);
    hipLaunchKernelGGL(k_out_pair, dim3(NN), dim3(256), 0, stream, a_buf, z, cat);
    hipLaunchKernelGGL(k_final, dim3(6, 8, 4), dim3(256), 0, stream, cat, Wout, bout, out);
}